// Round 2
// baseline (171.810 us; speedup 1.0000x reference)
//
#include <hip/hip_runtime.h>

#define BB 512
#define SS 512
#define TT 64
#define TSTRIDE 66   // transitions is (66,66)

__device__ __forceinline__ float lane_bcast(float v, int l) {
    return __int_as_float(__builtin_amdgcn_readlane(__float_as_int(v), l));
}
__device__ __forceinline__ float first_lane(float v) {
    return __int_as_float(__builtin_amdgcn_readfirstlane(__float_as_int(v)));
}

// One wave per batch. Lane j owns score[j] and E-column j (64 VGPRs).
// __launch_bounds__(64, 1): allow up to 512 VGPRs so Ecol stays resident
// (at the default occupancy target the compiler capped at 44 VGPRs and
// spilled Ecol to scratch -> 940 cy/step, VALUBusy 27%).
__global__ __launch_bounds__(64, 1) void crf_scan_kernel(
    const float* __restrict__ emissions,   // [B,S,T]
    const float* __restrict__ mask,        // [B,S]
    const float* __restrict__ trans,       // [66,66]
    float* __restrict__ logZ_out)          // [B]
{
    const int b = blockIdx.x;
    const int j = threadIdx.x;   // 0..63

    // E[i][j] = exp(tt[i][j]); lane j holds column j in registers.
    float Ecol[TT];
    #pragma unroll
    for (int i = 0; i < TT; ++i)
        Ecol[i] = __expf(trans[i * TSTRIDE + j]);

    const float* em = emissions + (size_t)b * SS * TT;
    const float* mk = mask + (size_t)b * SS;

    // score0[j] = (em[0,j] + trans[j, start=64]) * mask[b,0]
    float score = (em[j] + trans[j * TSTRIDE + TT]) * mk[0];

    // rolling emission prefetch, depth 3 (branchless clamped index)
    float e1 = em[1 * TT + j];
    float e2 = em[2 * TT + j];
    float e3 = em[3 * TT + j];
    float mv1 = mk[1];

    for (int s = 1; s < SS; ++s) {
        float emit = e1;
        float mval = mv1;
        e1 = e2; e2 = e3;
        int pf = s + 3 < SS - 1 ? s + 3 : SS - 1;
        e3 = em[pf * TT + j];
        int pm = s + 1 < SS - 1 ? s + 1 : SS - 1;
        mv1 = mk[pm];

        // cheap normalizer: any lane's score is within ~6 of the max
        float m0 = first_lane(score);
        float p  = __expf(score - m0);

        float a0 = 0.f, a1 = 0.f, a2 = 0.f, a3 = 0.f;
        #pragma unroll
        for (int i = 0; i < TT; i += 4) {
            a0 = __builtin_fmaf(lane_bcast(p, i + 0), Ecol[i + 0], a0);
            a1 = __builtin_fmaf(lane_bcast(p, i + 1), Ecol[i + 1], a1);
            a2 = __builtin_fmaf(lane_bcast(p, i + 2), Ecol[i + 2], a2);
            a3 = __builtin_fmaf(lane_bcast(p, i + 3), Ecol[i + 3], a3);
        }
        score = m0 + __logf((a0 + a1) + (a2 + a3)) + emit * mval;
    }

    // + trans[stop=65, j], then wave logsumexp
    score += trans[65 * TSTRIDE + j];

    float m = score;
    #pragma unroll
    for (int off = 32; off; off >>= 1) m = fmaxf(m, __shfl_xor(m, off));
    float e = __expf(score - m);
    #pragma unroll
    for (int off = 32; off; off >>= 1) e += __shfl_xor(e, off);
    if (j == 0) logZ_out[b] = m + __logf(e);
}

// One wave per batch: gold path score.
__global__ __launch_bounds__(64) void crf_gold_kernel(
    const float* __restrict__ emissions,
    const int* __restrict__ tags,          // [B,S] int32
    const float* __restrict__ mask,
    const float* __restrict__ trans,
    float* __restrict__ gold_out)          // [B]
{
    const int b = blockIdx.x;
    const int l = threadIdx.x;
    const int*   tg = tags + (size_t)b * SS;
    const float* mk = mask + (size_t)b * SS;
    const float* em = emissions + (size_t)b * SS * TT;

    float acc  = 0.f;
    float msum = 0.f;
    for (int s = l; s < SS; s += 64) {
        float m = mk[s];
        msum += m;
        if (s > 0) {
            int curr = tg[s], prev = tg[s - 1];
            acc += (trans[curr * TSTRIDE + prev] + em[s * TT + curr]) * m;
        } else {
            int t0 = tg[0];
            acc += (em[t0] + trans[t0 * TSTRIDE + TT]) * m;
        }
    }
    #pragma unroll
    for (int off = 32; off; off >>= 1) {
        acc  += __shfl_xor(acc,  off);
        msum += __shfl_xor(msum, off);
    }
    if (l == 0) {
        int len  = (int)(msum + 0.5f);
        int last = tg[len - 1];
        acc += trans[65 * TSTRIDE + last];
        gold_out[b] = acc;
    }
}

__global__ __launch_bounds__(256) void crf_final_kernel(
    const float* __restrict__ logZ,
    const float* __restrict__ gold,
    float* __restrict__ out)
{
    __shared__ float sdata[4];
    int t = threadIdx.x;
    float v = 0.f;
    for (int b = t; b < BB; b += 256) v += logZ[b] - gold[b];
    #pragma unroll
    for (int off = 32; off; off >>= 1) v += __shfl_xor(v, off);
    if ((t & 63) == 0) sdata[t >> 6] = v;
    __syncthreads();
    if (t == 0) out[0] = (sdata[0] + sdata[1] + sdata[2] + sdata[3]) * (1.0f / BB);
}

extern "C" void kernel_launch(void* const* d_in, const int* in_sizes, int n_in,
                              void* d_out, int out_size, void* d_ws, size_t ws_size,
                              hipStream_t stream) {
    const float* emissions = (const float*)d_in[0];
    const int*   tags      = (const int*)d_in[1];
    const float* mask      = (const float*)d_in[2];
    const float* trans     = (const float*)d_in[3];
    float* out  = (float*)d_out;
    float* logZ = (float*)d_ws;
    float* gold = logZ + BB;

    crf_gold_kernel<<<BB, 64, 0, stream>>>(emissions, tags, mask, trans, gold);
    crf_scan_kernel<<<BB, 64, 0, stream>>>(emissions, mask, trans, logZ);
    crf_final_kernel<<<1, 256, 0, stream>>>(logZ, gold, out);
}

// Round 4
// 145.970 us; speedup vs baseline: 1.1770x; 1.1770x over previous
//
#include <hip/hip_runtime.h>

#define BB 512
#define SS 512
#define TT 64
#define TSTRIDE 66   // transitions is (66,66)

typedef _Float16 h2 __attribute__((ext_vector_type(2)));

__device__ __forceinline__ float first_lane(float v) {
    return __int_as_float(__builtin_amdgcn_readfirstlane(__float_as_int(v)));
}

#if defined(__has_builtin)
#if __has_builtin(__builtin_amdgcn_fdot2)
#define FDOT2(a, b, c) __builtin_amdgcn_fdot2((a), (b), (c), false)
#endif
#endif
#ifndef FDOT2
#define FDOT2(a, b, c) ((c) + (float)(a).x * (float)(b).x + (float)(a).y * (float)(b).y)
#endif

#define DO32(F) F(0) F(1) F(2) F(3) F(4) F(5) F(6) F(7) \
                F(8) F(9) F(10) F(11) F(12) F(13) F(14) F(15) \
                F(16) F(17) F(18) F(19) F(20) F(21) F(22) F(23) \
                F(24) F(25) F(26) F(27) F(28) F(29) F(30) F(31)

// One wave per batch. Lane j owns score[j]; E column j lives in 32 named
// packed-f16 registers (NO arrays anywhere in the hot path -> no scratch;
// R1/R2 showed float Ecol[64] went to scratch regardless of launch_bounds).
__global__ __launch_bounds__(64, 1) void crf_fused_kernel(
    const float* __restrict__ emissions,   // [B,S,T]
    const int*   __restrict__ tags,        // [B,S]
    const float* __restrict__ mask,        // [B,S]
    const float* __restrict__ trans,       // [66,66]
    float* __restrict__ diff_out)          // [B] = logZ - gold
{
    const int b = blockIdx.x;
    const int j = threadIdx.x;   // 0..63
    const bool odd = (j & 1) != 0;

    const float* em = emissions + (size_t)b * SS * TT;
    const float* mk = mask + (size_t)b * SS;

    // E[i][j] = exp(tt[i][j]), packed {E[2K][j], E[2K+1][j]} as f16 pair (RNE).
#define EDECL(K) h2 E##K;
    DO32(EDECL)
#define EINIT(K) { float lo_ = __expf(trans[(2*(K)) * TSTRIDE + j]); \
                   float hi_ = __expf(trans[(2*(K)+1) * TSTRIDE + j]); \
                   h2 t_; t_.x = (_Float16)lo_; t_.y = (_Float16)hi_; E##K = t_; }
    DO32(EINIT)

    // score0[j] = (em[0,j] + trans[j, start=64]) * mask[b,0]
    float score = (em[j] + trans[j * TSTRIDE + TT]) * mk[0];

    // rolling emission prefetch, depth 3 (branchless clamped index)
    float e1 = em[1 * TT + j];
    float e2 = em[2 * TT + j];
    float e3 = em[3 * TT + j];
    float mv1 = mk[1];

    for (int s = 1; s < SS; ++s) {
        float emit = e1;
        float mval = mv1;
        e1 = e2; e2 = e3;
        int pf = s + 3 < SS - 1 ? s + 3 : SS - 1;
        e3 = em[pf * TT + j];
        int pm = s + 1 < SS - 1 ? s + 1 : SS - 1;
        mv1 = mk[pm];

        // normalizer: first lane + margin 4 keeps p in [e^-13, e^5] worst-case
        // (score spread across tags ~= emission spread + 0.4 <= ~9)
        float m0c = first_lane(score) + 4.0f;
        float p   = __expf(score - m0c);

        // pack {p_even, p_odd} per lane-pair: DPP quad-perm neighbor swap
#if defined(__has_builtin) && __has_builtin(__builtin_amdgcn_mov_dpp)
        float pn = __int_as_float(
            __builtin_amdgcn_mov_dpp(__float_as_int(p), 0xB1, 0xF, 0xF, true));
#else
        float pn = __shfl_xor(p, 1, 64);
#endif
        float lo = odd ? pn : p;
        float hi = odd ? p  : pn;
#if defined(__has_builtin) && __has_builtin(__builtin_amdgcn_cvt_pkrtz)
        h2 pk = __builtin_bit_cast(h2, __builtin_amdgcn_cvt_pkrtz(lo, hi));
#else
        h2 pk; pk.x = (_Float16)lo; pk.y = (_Float16)hi;
#endif
        int pki = __builtin_bit_cast(int, pk);

        float a0 = 0.f, a1 = 0.f, a2 = 0.f, a3 = 0.f;
#define DOT(K, A) { int rv_ = __builtin_amdgcn_readlane(pki, 2*(K)); \
                    h2 pv_ = __builtin_bit_cast(h2, rv_); \
                    A = FDOT2(pv_, E##K, A); }
        DOT(0,a0)  DOT(1,a1)  DOT(2,a2)  DOT(3,a3)
        DOT(4,a0)  DOT(5,a1)  DOT(6,a2)  DOT(7,a3)
        DOT(8,a0)  DOT(9,a1)  DOT(10,a2) DOT(11,a3)
        DOT(12,a0) DOT(13,a1) DOT(14,a2) DOT(15,a3)
        DOT(16,a0) DOT(17,a1) DOT(18,a2) DOT(19,a3)
        DOT(20,a0) DOT(21,a1) DOT(22,a2) DOT(23,a3)
        DOT(24,a0) DOT(25,a1) DOT(26,a2) DOT(27,a3)
        DOT(28,a0) DOT(29,a1) DOT(30,a2) DOT(31,a3)
#undef DOT

        float sum = (a0 + a1) + (a2 + a3);
        score = m0c + __logf(sum) + emit * mval;
    }

    // + trans[stop=65, j], then exact wave logsumexp (f32)
    score += trans[65 * TSTRIDE + j];
    float m = score;
    #pragma unroll
    for (int off = 32; off; off >>= 1) m = fmaxf(m, __shfl_xor(m, off));
    float e = __expf(score - m);
    #pragma unroll
    for (int off = 32; off; off >>= 1) e += __shfl_xor(e, off);
    float zres = m + __logf(e);   // valid in lane 0

    // ---- gold path score (fused tail; E regs dead by now) ----
    const int* tg = tags + (size_t)b * SS;
    float acc  = 0.f;
    float msum = 0.f;
    for (int s = j; s < SS; s += 64) {
        float mm = mk[s];
        msum += mm;
        if (s > 0) {
            int curr = tg[s], prev = tg[s - 1];
            acc += (trans[curr * TSTRIDE + prev] + em[s * TT + curr]) * mm;
        } else {
            int t0 = tg[0];
            acc += (em[t0] + trans[t0 * TSTRIDE + TT]) * mm;
        }
    }
    #pragma unroll
    for (int off = 32; off; off >>= 1) {
        acc  += __shfl_xor(acc,  off);
        msum += __shfl_xor(msum, off);
    }
    if (j == 0) {
        int len  = (int)(msum + 0.5f);
        int last = tg[len - 1];
        acc += trans[65 * TSTRIDE + last];
        diff_out[b] = zres - acc;
    }
}

__global__ __launch_bounds__(256) void crf_final_kernel(
    const float* __restrict__ diff,
    float* __restrict__ out)
{
    __shared__ float sdata[4];
    int t = threadIdx.x;
    float v = 0.f;
    for (int i = t; i < BB; i += 256) v += diff[i];
    #pragma unroll
    for (int off = 32; off; off >>= 1) v += __shfl_xor(v, off);
    if ((t & 63) == 0) sdata[t >> 6] = v;
    __syncthreads();
    if (t == 0) out[0] = (sdata[0] + sdata[1] + sdata[2] + sdata[3]) * (1.0f / BB);
}

extern "C" void kernel_launch(void* const* d_in, const int* in_sizes, int n_in,
                              void* d_out, int out_size, void* d_ws, size_t ws_size,
                              hipStream_t stream) {
    const float* emissions = (const float*)d_in[0];
    const int*   tags      = (const int*)d_in[1];
    const float* mask      = (const float*)d_in[2];
    const float* trans     = (const float*)d_in[3];
    float* out  = (float*)d_out;
    float* diff = (float*)d_ws;

    crf_fused_kernel<<<BB, 64, 0, stream>>>(emissions, tags, mask, trans, diff);
    crf_final_kernel<<<1, 256, 0, stream>>>(diff, out);
}